// Round 4
// baseline (52.578 us; speedup 1.0000x reference)
//
#include <hip/hip_runtime.h>
#include <hip/hip_bf16.h>

// 3x3 median pool, stride 1, zero-pad 1, fp32 in/out.
// Input: (8, 64, 256, 256) => 512 planes of 256x256.
// Each thread computes an 8-wide x 8-tall tile (64 outputs):
//   - loads 10 input rows x 10 cols once (1.25 load-rows per output-row),
//     all loads issued up front for max memory-level parallelism,
//   - per output row: exact median-of-9 via column-sort factorization
//     (v_min3/v_med3/v_max3).

__device__ __forceinline__ float min3f(float a, float b, float c) {
    return fminf(fminf(a, b), c);
}
__device__ __forceinline__ float max3f(float a, float b, float c) {
    return fmaxf(fmaxf(a, b), c);
}
__device__ __forceinline__ float med3f(float a, float b, float c) {
    return __builtin_amdgcn_fmed3f(a, b, c);
}

__global__ __launch_bounds__(256)
void median3x3_kernel(const float* __restrict__ x, float* __restrict__ y, int total) {
    int idx = blockIdx.x * blockDim.x + threadIdx.x;
    if (idx >= total) return;

    // Decomposition: 32 col-groups (8 wide) x 32 row-strips (8 tall) x 512 planes.
    const int w8 = idx & 31;
    const int hs = (idx >> 5) & 31;
    const int p  = idx >> 10;

    const float* plane = x + ((size_t)p << 16);   // 256*256 floats per plane
    const int c0 = w8 << 3;                        // first output column
    const int h0 = hs << 3;                        // first output row

    // Load 10 input rows (h0-1 .. h0+8) x 10 cols (c0-1 .. c0+8), zero padded.
    float r[10][10];
#pragma unroll
    for (int t = 0; t < 10; ++t) {
        const int hh = h0 + t - 1;
        if (hh < 0 || hh > 255) {
#pragma unroll
            for (int j = 0; j < 10; ++j) r[t][j] = 0.0f;
        } else {
            const float* row = plane + (hh << 8);
            const float4 a = *reinterpret_cast<const float4*>(row + c0);
            const float4 b = *reinterpret_cast<const float4*>(row + c0 + 4);
            r[t][1] = a.x; r[t][2] = a.y; r[t][3] = a.z; r[t][4] = a.w;
            r[t][5] = b.x; r[t][6] = b.y; r[t][7] = b.z; r[t][8] = b.w;
            r[t][0] = (c0 > 0)       ? row[c0 - 1] : 0.0f;
            r[t][9] = (c0 + 8 < 256) ? row[c0 + 8] : 0.0f;
        }
    }

    float* outbase = y + ((size_t)p << 16) + ((size_t)h0 << 8) + c0;

#pragma unroll
    for (int orow = 0; orow < 8; ++orow) {
        // Column-wise vertical sort over rows orow..orow+2.
        float lo[10], mi[10], hi[10];
#pragma unroll
        for (int j = 0; j < 10; ++j) {
            const float a = r[orow][j], b = r[orow + 1][j], c = r[orow + 2][j];
            lo[j] = min3f(a, b, c);
            mi[j] = med3f(a, b, c);
            hi[j] = max3f(a, b, c);
        }
        float res[8];
#pragma unroll
        for (int k = 0; k < 8; ++k) {
            const float A = max3f(lo[k], lo[k + 1], lo[k + 2]);
            const float B = med3f(mi[k], mi[k + 1], mi[k + 2]);
            const float C = min3f(hi[k], hi[k + 1], hi[k + 2]);
            res[k] = med3f(A, B, C);
        }
        float* out = outbase + (orow << 8);
        *reinterpret_cast<float4*>(out)     = make_float4(res[0], res[1], res[2], res[3]);
        *reinterpret_cast<float4*>(out + 4) = make_float4(res[4], res[5], res[6], res[7]);
    }
}

extern "C" void kernel_launch(void* const* d_in, const int* in_sizes, int n_in,
                              void* d_out, int out_size, void* d_ws, size_t ws_size,
                              hipStream_t stream) {
    const float* x = (const float*)d_in[0];
    float* y = (float*)d_out;
    const int total = out_size / 64;            // 524,288 threads (8x8 tiles)
    const int threads = 256;
    const int blocks = (total + threads - 1) / threads;
    median3x3_kernel<<<blocks, threads, 0, stream>>>(x, y, total);
}